// Round 7
// baseline (317.118 us; speedup 1.0000x reference)
//
#include <hip/hip_runtime.h>
#include <hip/hip_bf16.h>

// TransformerLayer on MI355X (gfx950). Round 7:
//  attn_fused rewritten for MFMA density:
//   - QBLK=64, TK=64, grid 512 (2/CU, descending qt for greedy balance)
//   - NO K/V LDS staging: K/V B-fragments direct global->reg (L2-resident;
//     bh->XCD mapping keeps 2 bh per XCD ~ 4MB = L2)
//   - LDS only for P-tile (double-buffered, 16KB) + rowsum reduce
//   - ONE barrier per K-tile (P-dbuf + lgkmcnt(0) drain before barrier)
//   - P dumped to pout straight from registers as f32
//  GEMM stack unchanged from round 6 (passed).

typedef __bf16 bf16_t;
typedef __bf16 bf16x8 __attribute__((ext_vector_type(8)));
typedef __bf16 bf16x4 __attribute__((ext_vector_type(4)));
typedef float  f32x4  __attribute__((ext_vector_type(4)));

#define DEV __device__ __forceinline__

DEV f32x4 mfma16(bf16x8 a, bf16x8 b, f32x4 c) {
  return __builtin_amdgcn_mfma_f32_16x16x32_bf16(a, b, c, 0, 0, 0);
}

DEV void gload16(const void* g, void* l) {
  __builtin_amdgcn_global_load_lds(
      (const __attribute__((address_space(1))) unsigned int*)g,
      (__attribute__((address_space(3))) unsigned int*)l, 16, 0, 0);
}

// ---------------- fused LN1 + weight cvt (grid 1024 + 2560) ----------------
__global__ __launch_bounds__(256) void k1_lncvt(
    const float* __restrict__ x, const float* __restrict__ g, const float* __restrict__ bta,
    float* __restrict__ of, bf16_t* __restrict__ ob,
    const float* __restrict__ s0, const float* __restrict__ s1,
    const float* __restrict__ s2, const float* __restrict__ s3,
    const float* __restrict__ s4, const float* __restrict__ s5,
    bf16_t* __restrict__ d0, bf16_t* __restrict__ d1, bf16_t* __restrict__ d2,
    bf16_t* __restrict__ d3, bf16_t* __restrict__ d4, bf16_t* __restrict__ d5) {
  int bid = blockIdx.x;
  if (bid < 1024) {
    int row = bid * 4 + (threadIdx.x >> 6);
    int l = threadIdx.x & 63;
    const float4 v = *(const float4*)(x + (size_t)row * 256 + l * 4);
    float s  = v.x + v.y + v.z + v.w;
    float s2 = v.x*v.x + v.y*v.y + v.z*v.z + v.w*v.w;
#pragma unroll
    for (int o = 1; o < 64; o <<= 1) { s += __shfl_xor(s, o, 64); s2 += __shfl_xor(s2, o, 64); }
    float m   = s * (1.f/256.f);
    float var = s2 * (1.f/256.f) - m * m;
    float rs  = rsqrtf(var + 1e-9f);
    const float4 gv = *(const float4*)(g   + l * 4);
    const float4 bv = *(const float4*)(bta + l * 4);
    float4 y;
    y.x = (v.x - m) * rs * gv.x + bv.x;
    y.y = (v.y - m) * rs * gv.y + bv.y;
    y.z = (v.z - m) * rs * gv.z + bv.z;
    y.w = (v.w - m) * rs * gv.w + bv.w;
    *(float4*)(of + (size_t)row * 256 + l * 4) = y;
    bf16x4 yb = { (bf16_t)y.x, (bf16_t)y.y, (bf16_t)y.z, (bf16_t)y.w };
    *(bf16x4*)(ob + (size_t)row * 256 + l * 4) = yb;
  } else {
    int i = (bid - 1024) * 256 + threadIdx.x;
    const float* s; bf16_t* d; int off;
    if      (i < 131072) { s = s0; d = d0; off = i; }
    else if (i < 262144) { s = s1; d = d1; off = i - 131072; }
    else if (i < 393216) { s = s2; d = d2; off = i - 262144; }
    else if (i < 524288) { s = s3; d = d3; off = i - 393216; }
    else if (i < 589824) { s = s4; d = d4; off = i - 524288; }
    else                 { s = s5; d = d5; off = i - 589824; }
    float4 v = ((const float4*)s)[off];
    bf16x4 o = { (bf16_t)v.x, (bf16_t)v.y, (bf16_t)v.z, (bf16_t)v.w };
    ((bf16x4*)d)[off] = o;
  }
}

// ---------------- 2-phase double-buffered 128x128 GEMM core ----------------
DEV void gemm_core(const bf16_t* __restrict__ A, const bf16_t* __restrict__ W,
                   int lda, int row0, int col0, int k0, int kiters,
                   char* Asb, char* Bsb, f32x4 (&acc)[4][4]) {
  int tid = threadIdx.x, w = tid >> 6, l = tid & 63, l15 = l & 15, lhi = l >> 4;
  int wr = (w >> 1) * 64, wc = (w & 1) * 64;

#define STAGE(buf, kk) do {                                                   \
    char* Ad = Asb + (buf) * 8192 + w * 1024;                                 \
    char* Bd = Bsb + (buf) * 8192 + w * 1024;                                 \
    _Pragma("unroll")                                                         \
    for (int j = 0; j < 2; ++j) {                                             \
      int idx = (j * 256 + tid) * 8; int r = idx >> 5, c = idx & 31;          \
      gload16(A + (size_t)(row0 + r) * lda + (kk) + c, Ad + j * 4096);        \
      gload16(W + (size_t)(col0 + r) * lda + (kk) + c, Bd + j * 4096);        \
    } } while (0)

  STAGE(0, k0);
  for (int t = 0; t < kiters; ++t) {
    int cur = t & 1;
    if (t + 1 < kiters) {
      STAGE(cur ^ 1, k0 + (t + 1) * 32);
      asm volatile("s_waitcnt vmcnt(4)" ::: "memory");
    } else {
      asm volatile("s_waitcnt vmcnt(0)" ::: "memory");
    }
    __builtin_amdgcn_s_barrier();
    asm volatile("" ::: "memory");
    const bf16_t* As = (const bf16_t*)(Asb + cur * 8192);
    const bf16_t* Bs = (const bf16_t*)(Bsb + cur * 8192);
    bf16x8 af[4], bfr[4];
#pragma unroll
    for (int m = 0; m < 4; ++m)
      af[m] = *(const bf16x8*)(As + (wr + 16 * m + l15) * 32 + lhi * 8);
#pragma unroll
    for (int n = 0; n < 4; ++n)
      bfr[n] = *(const bf16x8*)(Bs + (wc + 16 * n + l15) * 32 + lhi * 8);
#pragma unroll
    for (int m = 0; m < 4; ++m)
#pragma unroll
      for (int n = 0; n < 4; ++n)
        acc[m][n] = mfma16(af[m], bfr[n], acc[m][n]);
    asm volatile("s_waitcnt lgkmcnt(0)" ::: "memory");
    __builtin_amdgcn_s_barrier();
  }
#undef STAGE
}

// ---------------- fused QKV: grid (48, 32); V writes V^T via LDS transpose ----------------
__global__ __launch_bounds__(256, 4) void gemm_qkv(
    const bf16_t* __restrict__ A,
    const bf16_t* __restrict__ W0, const bf16_t* __restrict__ W1, const bf16_t* __restrict__ W2,
    const float* __restrict__ b0, const float* __restrict__ b1, const float* __restrict__ b2,
    bf16_t* __restrict__ qo, bf16_t* __restrict__ ko, bf16_t* __restrict__ vto) {
  __shared__ char smem[34816];   // staging 32KB | V-transpose 128x136 bf16
  char* Asb = smem;
  char* Bsb = smem + 16384;
  int bx = blockIdx.x;
  int wsel = bx >> 4, cb = bx & 15;
  const bf16_t* W    = wsel == 0 ? W0 : (wsel == 1 ? W1 : W2);
  const float*  bias = wsel == 0 ? b0 : (wsel == 1 ? b1 : b2);
  int row0 = blockIdx.y * 128, col0 = cb * 128;
  f32x4 acc[4][4] = {};
  gemm_core(A, W, 256, row0, col0, 0, 8, Asb, Bsb, acc);

  int tid = threadIdx.x, w = tid >> 6, l = tid & 63, l15 = l & 15, lhi = l >> 4;
  int wr = (w >> 1) * 64, wc = (w & 1) * 64;

  if (wsel < 2) {
    bf16_t* out = wsel == 0 ? qo : ko;
#pragma unroll
    for (int m = 0; m < 4; ++m)
#pragma unroll
      for (int n = 0; n < 4; ++n)
#pragma unroll
        for (int j = 0; j < 4; ++j) {
          int row = row0 + wr + 16 * m + lhi * 4 + j;
          int col = col0 + wc + 16 * n + l15;
          float v = acc[m][n][j] + bias[col];
          out[((size_t)((row >> 11) * 8 + (col >> 8)) * 2048 + (row & 2047)) * 256 + (col & 255)] = (bf16_t)v;
        }
  } else {
    // V: transpose in LDS, write V^T (B,H,Dh,S)
    __syncthreads();   // full drain before overwriting staging LDS
    bf16_t* T = (bf16_t*)smem;   // [128 d][136 stride] bf16
#pragma unroll
    for (int m = 0; m < 4; ++m)
#pragma unroll
      for (int n = 0; n < 4; ++n) {
        int d = wc + 16 * n + l15;
        int s = wr + 16 * m + lhi * 4;
        bf16x4 v4;
#pragma unroll
        for (int j = 0; j < 4; ++j) v4[j] = (bf16_t)(acc[m][n][j] + bias[col0 + d]);
        *(bf16x4*)(T + d * 136 + s) = v4;
      }
    __syncthreads();
    int bh = ((row0 >> 11) << 3) + (col0 >> 8);
    int d0 = col0 & 255, s0g = row0 & 2047;
#pragma unroll
    for (int p = 0; p < 8; ++p) {
      int idx = p * 256 + tid;
      int d = idx >> 4, c = (idx & 15) * 8;
      bf16x8 v8 = *(const bf16x8*)(T + d * 136 + c);
      *(bf16x8*)(vto + ((size_t)bh * 256 + d0 + d) * 2048 + s0g + c) = v8;
    }
  }
}

// ---------------- split-K partial GEMM: N=256, grid (2, 32, 4) ----------------
__global__ __launch_bounds__(256, 4) void gemm_part(
    const bf16_t* __restrict__ A, const bf16_t* __restrict__ W,
    int lda, int ksub, float* __restrict__ parts) {
  __shared__ char Asb[2 * 8192];
  __shared__ char Bsb[2 * 8192];
  int z = blockIdx.z;
  int row0 = blockIdx.y * 128, col0 = blockIdx.x * 128;
  f32x4 acc[4][4] = {};
  gemm_core(A, W, lda, row0, col0, z * ksub, ksub >> 5, Asb, Bsb, acc);

  int tid = threadIdx.x, w = tid >> 6, l = tid & 63, l15 = l & 15, lhi = l >> 4;
  int wr = (w >> 1) * 64, wc = (w & 1) * 64;
  float* p = parts + (size_t)z * 1048576;
#pragma unroll
  for (int m = 0; m < 4; ++m)
#pragma unroll
    for (int n = 0; n < 4; ++n)
#pragma unroll
      for (int j = 0; j < 4; ++j) {
        int row = row0 + wr + 16 * m + lhi * 4 + j;
        int col = col0 + wc + 16 * n + l15;
        p[(size_t)row * 256 + col] = acc[m][n][j];
      }
}

// ---------------- reduce 4 partials + bias + residual (final out) ----------------
__global__ __launch_bounds__(256) void reduce4(
    const float* __restrict__ parts, const float* __restrict__ bias,
    const float* __restrict__ res, float* __restrict__ out) {
  int i = blockIdx.x * 256 + threadIdx.x;
  f32x4 s = *(const f32x4*)(parts + (size_t)i * 4);
  s += *(const f32x4*)(parts + 1048576 + (size_t)i * 4);
  s += *(const f32x4*)(parts + 2097152 + (size_t)i * 4);
  s += *(const f32x4*)(parts + 3145728 + (size_t)i * 4);
  s += *(const f32x4*)(res + (size_t)i * 4);
  s += *(const f32x4*)(bias + (i & 63) * 4);
  *(f32x4*)(out + (size_t)i * 4) = s;
}

// ---------------- fused dense-reduce + residual + LN2 ----------------
__global__ __launch_bounds__(256) void reduce_ln(
    const float* __restrict__ parts, const float* __restrict__ bias,
    const float* __restrict__ res, const float* __restrict__ g,
    const float* __restrict__ bta, float* __restrict__ x1o, bf16_t* __restrict__ mo) {
  int row = blockIdx.x * 4 + (threadIdx.x >> 6);
  int l = threadIdx.x & 63;
  size_t base = (size_t)row * 256 + l * 4;
  f32x4 s = *(const f32x4*)(parts + base);
  s += *(const f32x4*)(parts + 1048576 + base);
  s += *(const f32x4*)(parts + 2097152 + base);
  s += *(const f32x4*)(parts + 3145728 + base);
  s += *(const f32x4*)(res + base);
  s += *(const f32x4*)(bias + l * 4);
  *(f32x4*)(x1o + base) = s;
  float sm = s[0] + s[1] + s[2] + s[3];
  float s2 = s[0]*s[0] + s[1]*s[1] + s[2]*s[2] + s[3]*s[3];
#pragma unroll
  for (int o = 1; o < 64; o <<= 1) { sm += __shfl_xor(sm, o, 64); s2 += __shfl_xor(s2, o, 64); }
  float m   = sm * (1.f/256.f);
  float var = s2 * (1.f/256.f) - m * m;
  float rs  = rsqrtf(var + 1e-9f);
  const float4 gv = *(const float4*)(g   + l * 4);
  const float4 bv = *(const float4*)(bta + l * 4);
  bf16x4 yb;
  yb[0] = (bf16_t)((s[0] - m) * rs * gv.x + bv.x);
  yb[1] = (bf16_t)((s[1] - m) * rs * gv.y + bv.y);
  yb[2] = (bf16_t)((s[2] - m) * rs * gv.z + bv.z);
  yb[3] = (bf16_t)((s[3] - m) * rs * gv.w + bv.w);
  *(bf16x4*)(mo + base) = yb;
}

// ---------------- FC1 with gelu ----------------
__global__ __launch_bounds__(256, 4) void gemm_fc1(
    const bf16_t* __restrict__ A, const bf16_t* __restrict__ W,
    const float* __restrict__ bias, bf16_t* __restrict__ out) {
  __shared__ char Asb[2 * 8192];
  __shared__ char Bsb[2 * 8192];
  int row0 = blockIdx.y * 128, col0 = blockIdx.x * 128;
  f32x4 acc[4][4] = {};
  gemm_core(A, W, 256, row0, col0, 0, 8, Asb, Bsb, acc);

  int tid = threadIdx.x, w = tid >> 6, l = tid & 63, l15 = l & 15, lhi = l >> 4;
  int wr = (w >> 1) * 64, wc = (w & 1) * 64;
#pragma unroll
  for (int m = 0; m < 4; ++m)
#pragma unroll
    for (int n = 0; n < 4; ++n)
#pragma unroll
      for (int j = 0; j < 4; ++j) {
        int row = row0 + wr + 16 * m + lhi * 4 + j;
        int col = col0 + wc + 16 * n + l15;
        float t = acc[m][n][j] + bias[col];
        float ge = 0.5f * t * (1.f + tanhf(0.7978845608f * t * (1.f + 0.044715f * t * t)));
        out[(size_t)row * 1024 + col] = (bf16_t)ge;
      }
}

// ---------------- fused attention v2: QBLK=64, TK=64, no K/V LDS ----------------
// grid 512: bh = (bx&7)|((bx>>3)&1)<<3 (XCD sees 2 bh), qt = 31-(bx>>4) (big first)
__global__ __launch_bounds__(256, 2) void attn_fused(
    const bf16_t* __restrict__ qg, const bf16_t* __restrict__ kg,
    const bf16_t* __restrict__ vt, float* __restrict__ pout,
    bf16_t* __restrict__ ctxo) {
  __shared__ __align__(16) char smem[17408];  // P dbuf 2x8KB | sl 512B | invsh 256B
  char*  Psh   = smem;
  float* sl    = (float*)(smem + 16384);
  float* invsh = (float*)(smem + 16896);
  int bx = blockIdx.x;
  int bh = (bx & 7) | (((bx >> 3) & 1) << 3);
  int qt = 31 - (bx >> 4);
  int tid = threadIdx.x, w = tid >> 6, l = tid & 63;
  int l15 = l & 15, lhi = l >> 4;
  int wm = w >> 1, wn = w & 1;
  const bf16_t* Q = qg + (size_t)bh * 2048 * 256;
  const bf16_t* K = kg + (size_t)bh * 2048 * 256;
  const bf16_t* V = vt + (size_t)bh * 256 * 2048;
  int qbase = qt * 64;

  // Q fragments: wave-half wm owns rows [qbase+wm*32, +32)
  bf16x8 qf[2][8];
#pragma unroll
  for (int m = 0; m < 2; ++m)
#pragma unroll
    for (int ks = 0; ks < 8; ++ks)
      qf[m][ks] = *(const bf16x8*)(Q + (size_t)(qbase + wm * 32 + m * 16 + l15) * 256 + ks * 32 + lhi * 8);

  // ---- pass A: masked exp rowsums; no LDS, no barriers; K direct from L2 ----
  float sums[2][4] = {};
  for (int t = 0; t <= qt; ++t) {
    const bf16_t* Kt = K + (size_t)(t * 64 + wn * 32) * 256;
    f32x4 acc[2][2] = {};
#pragma unroll
    for (int ks = 0; ks < 8; ++ks) {
      bf16x8 kb0 = *(const bf16x8*)(Kt + (size_t)l15 * 256 + ks * 32 + lhi * 8);
      bf16x8 kb1 = *(const bf16x8*)(Kt + (size_t)(16 + l15) * 256 + ks * 32 + lhi * 8);
      acc[0][0] = mfma16(qf[0][ks], kb0, acc[0][0]);
      acc[0][1] = mfma16(qf[0][ks], kb1, acc[0][1]);
      acc[1][0] = mfma16(qf[1][ks], kb0, acc[1][0]);
      acc[1][1] = mfma16(qf[1][ks], kb1, acc[1][1]);
    }
    if (t < qt) {
#pragma unroll
      for (int m = 0; m < 2; ++m)
#pragma unroll
        for (int n = 0; n < 2; ++n)
#pragma unroll
          for (int j = 0; j < 4; ++j)
            sums[m][j] += __expf(acc[m][n][j] * 0.0625f);
    } else {
#pragma unroll
      for (int m = 0; m < 2; ++m)
#pragma unroll
        for (int n = 0; n < 2; ++n)
#pragma unroll
          for (int j = 0; j < 4; ++j) {
            int qr = qbase + wm * 32 + m * 16 + lhi * 4 + j;
            int kc = t * 64 + wn * 32 + n * 16 + l15;
            sums[m][j] += (kc <= qr) ? __expf(acc[m][n][j] * 0.0625f) : 0.f;
          }
    }
  }
  // reduce over l15 within each lhi group, combine wn-halves via LDS
#pragma unroll
  for (int m = 0; m < 2; ++m)
#pragma unroll
    for (int j = 0; j < 4; ++j)
#pragma unroll
      for (int o = 1; o < 16; o <<= 1)
        sums[m][j] += __shfl_xor(sums[m][j], o, 64);
  if (l15 == 0)
#pragma unroll
    for (int m = 0; m < 2; ++m)
#pragma unroll
      for (int j = 0; j < 4; ++j)
        sl[wn * 64 + wm * 32 + m * 16 + lhi * 4 + j] = sums[m][j];
  __syncthreads();
  if (tid < 64) invsh[tid] = 1.f / (sl[tid] + sl[64 + tid]);
  __syncthreads();

  float inv[2][4];
#pragma unroll
  for (int m = 0; m < 2; ++m)
#pragma unroll
    for (int j = 0; j < 4; ++j)
      inv[m][j] = invsh[wm * 32 + m * 16 + lhi * 4 + j];

  // ---- pass B: QK -> P(LDS dbuf)+dump(f32 regs->HBM) -> PV; 1 barrier/tile ----
  f32x4 ctx[4][4] = {};
  for (int t = 0; t <= qt; ++t) {
    char* Pb = Psh + (t & 1) * 8192;   // [64 rows][64 cols] bf16, 128B rows, swz ((r&7)<<4)
    const bf16_t* Kt = K + (size_t)(t * 64 + wn * 32) * 256;

    // QK: wave (wm,wn): rows [wm*32,+32) x cols [wn*32,+32)
    f32x4 acc[2][2] = {};
#pragma unroll
    for (int ks = 0; ks < 8; ++ks) {
      bf16x8 kb0 = *(const bf16x8*)(Kt + (size_t)l15 * 256 + ks * 32 + lhi * 8);
      bf16x8 kb1 = *(const bf16x8*)(Kt + (size_t)(16 + l15) * 256 + ks * 32 + lhi * 8);
      acc[0][0] = mfma16(qf[0][ks], kb0, acc[0][0]);
      acc[0][1] = mfma16(qf[0][ks], kb1, acc[0][1]);
      acc[1][0] = mfma16(qf[1][ks], kb0, acc[1][0]);
      acc[1][1] = mfma16(qf[1][ks], kb1, acc[1][1]);
    }
    // exp + normalize; write Psh quarter (bf16) + dump f32 to pout from regs
    bool full = (t < qt);
#pragma unroll
    for (int m = 0; m < 2; ++m)
#pragma unroll
      for (int n = 0; n < 2; ++n)
#pragma unroll
        for (int j = 0; j < 4; ++j) {
          int rr = wm * 32 + m * 16 + lhi * 4 + j;
          int cc = wn * 32 + n * 16 + l15;
          float e = __expf(acc[m][n][j] * 0.0625f) * inv[m][j];
          if (!full && cc > qbase + rr - t * 64) e = 0.f;   // kc = t*64+cc > qr
          int byte = rr * 128 + cc * 2;
          *(bf16_t*)(Pb + (byte ^ ((rr & 7) << 4))) = (bf16_t)e;
          pout[((size_t)bh * 2048 + qbase + rr) * 2048 + t * 64 + cc] = e;
        }
    // V fragments for this tile (independent of Psh; latency hides under barrier)
    bf16x8 vb[4][2];
#pragma unroll
    for (int n4 = 0; n4 < 4; ++n4)
#pragma unroll
      for (int ks2 = 0; ks2 < 2; ++ks2)
        vb[n4][ks2] = *(const bf16x8*)(V + (size_t)(w * 64 + n4 * 16 + l15) * 2048 + t * 64 + ks2 * 32 + lhi * 8);

    asm volatile("s_waitcnt lgkmcnt(0)" ::: "memory");   // P writes (and prior pa reads) drained
    __builtin_amdgcn_s_barrier();
    asm volatile("" ::: "memory");

    // PV: wave w -> d-cols [w*64,+64), all 64 q-rows
    __builtin_amdgcn_s_setprio(1);
#pragma unroll
    for (int ks2 = 0; ks2 < 2; ++ks2) {
      bf16x8 pa[4];
#pragma unroll
      for (int m4 = 0; m4 < 4; ++m4) {
        int pr = m4 * 16 + l15;
        pa[m4] = *(const bf16x8*)(Pb + ((pr * 128 + ks2 * 64 + lhi * 16) ^ ((pr & 7) << 4)));
      }
#pragma unroll
      for (int m4 = 0; m4 < 4; ++m4)
#pragma unroll
        for (int n4 = 0; n4 < 4; ++n4)
          ctx[m4][n4] = mfma16(pa[m4], vb[n4][ks2], ctx[m4][n4]);
    }
    __builtin_amdgcn_s_setprio(0);
  }

  // ctx write: (b, s, h*256 + d) bf16
  int b = bh >> 3, h = bh & 7;
#pragma unroll
  for (int m4 = 0; m4 < 4; ++m4)
#pragma unroll
    for (int n4 = 0; n4 < 4; ++n4)
#pragma unroll
      for (int j = 0; j < 4; ++j) {
        int qr = qbase + m4 * 16 + lhi * 4 + j;
        ctxo[((size_t)b * 2048 + qr) * 2048 + h * 256 + w * 64 + n4 * 16 + l15] = (bf16_t)ctx[m4][n4][j];
      }

  // zero-fill masked upper region
  int zs = qbase + 64;
  for (int r = 0; r < 64; ++r) {
    size_t base2 = ((size_t)bh * 2048 + qbase + r) * 2048;
    for (int c = zs + tid * 4; c < 2048; c += 1024)
      *(float4*)(pout + base2 + c) = make_float4(0.f, 0.f, 0.f, 0.f);
  }
}

// ---------------- host launch ----------------
extern "C" void kernel_launch(void* const* d_in, const int* in_sizes, int n_in,
                              void* d_out, int out_size, void* d_ws, size_t ws_size,
                              hipStream_t stream) {
  const float* x     = (const float*)d_in[0];
  const float* ln1g  = (const float*)d_in[2];
  const float* ln1b  = (const float*)d_in[3];
  const float* wq_w  = (const float*)d_in[4];
  const float* wq_b  = (const float*)d_in[5];
  const float* wk_w  = (const float*)d_in[6];
  const float* wk_b  = (const float*)d_in[7];
  const float* wv_w  = (const float*)d_in[8];
  const float* wv_b  = (const float*)d_in[9];
  const float* dw    = (const float*)d_in[10];
  const float* db    = (const float*)d_in[11];
  const float* ln2g  = (const float*)d_in[12];
  const float* ln2b  = (const float*)d_in[13];
  const float* f1w   = (const float*)d_in[14];
  const float* f1b   = (const float*)d_in[15];
  const float* f2w   = (const float*)d_in[16];
  const float* f2b   = (const float*)d_in[17];

  char* ws = (char*)d_ws;
  const size_t MB = 1u << 20;
  float*  xn_f = (float*) (ws + 0 * MB);
  bf16_t* xn_b = (bf16_t*)(ws + 4 * MB);
  bf16_t* q_b  = (bf16_t*)(ws + 6 * MB);
  bf16_t* k_b  = (bf16_t*)(ws + 22 * MB);
  bf16_t* ctx_b= (bf16_t*)(ws + 38 * MB);
  bf16_t* vt_b = (bf16_t*)(ws + 54 * MB);
  float*  x1_f = (float*) (ws + 70 * MB);
  bf16_t* m_b  = (bf16_t*)(ws + 74 * MB);
  bf16_t* h_b  = (bf16_t*)(ws + 76 * MB);
  bf16_t* wq_bf = (bf16_t*)(ws + 84 * MB);
  bf16_t* wk_bf = wq_bf + 524288;
  bf16_t* wv_bf = wk_bf + 524288;
  bf16_t* dw_bf = wv_bf + 524288;
  bf16_t* f1_bf = dw_bf + 524288;
  bf16_t* f2_bf = f1_bf + 262144;
  float* parts_d = (float*)q_b;
  float* parts_f = (float*)k_b;

  float* out0 = (float*)d_out;
  float* pout = out0 + 1048576;

  k1_lncvt<<<3584, 256, 0, stream>>>(x, ln1g, ln1b, xn_f, xn_b,
                                     wq_w, wk_w, wv_w, dw, f1w, f2w,
                                     wq_bf, wk_bf, wv_bf, dw_bf, f1_bf, f2_bf);

  gemm_qkv<<<dim3(48, 32), 256, 0, stream>>>(xn_b, wq_bf, wk_bf, wv_bf,
                                             wq_b, wk_b, wv_b, q_b, k_b, vt_b);

  attn_fused<<<512, 256, 0, stream>>>(q_b, k_b, vt_b, pout, ctx_b);

  gemm_part<<<dim3(2, 32, 4), 256, 0, stream>>>(ctx_b, dw_bf, 2048, 512, parts_d);
  reduce_ln<<<1024, 256, 0, stream>>>(parts_d, db, xn_f, ln2g, ln2b, x1_f, m_b);

  gemm_fc1<<<dim3(8, 32), 256, 0, stream>>>(m_b, f1_bf, f1b, h_b);

  gemm_part<<<dim3(2, 32, 4), 256, 0, stream>>>(h_b, f2_bf, 1024, 256, parts_f);
  reduce4<<<1024, 256, 0, stream>>>(parts_f, f2b, x1_f, out0);
}

// Round 8
// 231.945 us; speedup vs baseline: 1.3672x; 1.3672x over previous
//
#include <hip/hip_runtime.h>
#include <hip/hip_bf16.h>

// TransformerLayer on MI355X (gfx950). Round 8:
//  attn_fused v3: QBLK=32, TK=64, grid 1024 (LPT backfill balance).
//  K staged global_load_lds dbuf (pre-swizzled source, (r&15)<<4), ONE
//  barrier/tile with counted vmcnt(16); V direct global->reg prefetched at
//  iter top; P LDS dbuf + reg->f32 dump. Rowsums fused (pass A, 1 barrier/tile).
//  GEMM stack unchanged (R5/R6 passing config).

typedef __bf16 bf16_t;
typedef __bf16 bf16x8 __attribute__((ext_vector_type(8)));
typedef __bf16 bf16x4 __attribute__((ext_vector_type(4)));
typedef float  f32x4  __attribute__((ext_vector_type(4)));

#define DEV __device__ __forceinline__

DEV f32x4 mfma16(bf16x8 a, bf16x8 b, f32x4 c) {
  return __builtin_amdgcn_mfma_f32_16x16x32_bf16(a, b, c, 0, 0, 0);
}

DEV void gload16(const void* g, void* l) {
  __builtin_amdgcn_global_load_lds(
      (const __attribute__((address_space(1))) unsigned int*)g,
      (__attribute__((address_space(3))) unsigned int*)l, 16, 0, 0);
}

// ---------------- fused LN1 + weight cvt (grid 1024 + 2560) ----------------
__global__ __launch_bounds__(256) void k1_lncvt(
    const float* __restrict__ x, const float* __restrict__ g, const float* __restrict__ bta,
    float* __restrict__ of, bf16_t* __restrict__ ob,
    const float* __restrict__ s0, const float* __restrict__ s1,
    const float* __restrict__ s2, const float* __restrict__ s3,
    const float* __restrict__ s4, const float* __restrict__ s5,
    bf16_t* __restrict__ d0, bf16_t* __restrict__ d1, bf16_t* __restrict__ d2,
    bf16_t* __restrict__ d3, bf16_t* __restrict__ d4, bf16_t* __restrict__ d5) {
  int bid = blockIdx.x;
  if (bid < 1024) {
    int row = bid * 4 + (threadIdx.x >> 6);
    int l = threadIdx.x & 63;
    const float4 v = *(const float4*)(x + (size_t)row * 256 + l * 4);
    float s  = v.x + v.y + v.z + v.w;
    float s2 = v.x*v.x + v.y*v.y + v.z*v.z + v.w*v.w;
#pragma unroll
    for (int o = 1; o < 64; o <<= 1) { s += __shfl_xor(s, o, 64); s2 += __shfl_xor(s2, o, 64); }
    float m   = s * (1.f/256.f);
    float var = s2 * (1.f/256.f) - m * m;
    float rs  = rsqrtf(var + 1e-9f);
    const float4 gv = *(const float4*)(g   + l * 4);
    const float4 bv = *(const float4*)(bta + l * 4);
    float4 y;
    y.x = (v.x - m) * rs * gv.x + bv.x;
    y.y = (v.y - m) * rs * gv.y + bv.y;
    y.z = (v.z - m) * rs * gv.z + bv.z;
    y.w = (v.w - m) * rs * gv.w + bv.w;
    *(float4*)(of + (size_t)row * 256 + l * 4) = y;
    bf16x4 yb = { (bf16_t)y.x, (bf16_t)y.y, (bf16_t)y.z, (bf16_t)y.w };
    *(bf16x4*)(ob + (size_t)row * 256 + l * 4) = yb;
  } else {
    int i = (bid - 1024) * 256 + threadIdx.x;
    const float* s; bf16_t* d; int off;
    if      (i < 131072) { s = s0; d = d0; off = i; }
    else if (i < 262144) { s = s1; d = d1; off = i - 131072; }
    else if (i < 393216) { s = s2; d = d2; off = i - 262144; }
    else if (i < 524288) { s = s3; d = d3; off = i - 393216; }
    else if (i < 589824) { s = s4; d = d4; off = i - 524288; }
    else                 { s = s5; d = d5; off = i - 589824; }
    float4 v = ((const float4*)s)[off];
    bf16x4 o = { (bf16_t)v.x, (bf16_t)v.y, (bf16_t)v.z, (bf16_t)v.w };
    ((bf16x4*)d)[off] = o;
  }
}

// ---------------- 2-phase double-buffered 128x128 GEMM core ----------------
DEV void gemm_core(const bf16_t* __restrict__ A, const bf16_t* __restrict__ W,
                   int lda, int row0, int col0, int k0, int kiters,
                   char* Asb, char* Bsb, f32x4 (&acc)[4][4]) {
  int tid = threadIdx.x, w = tid >> 6, l = tid & 63, l15 = l & 15, lhi = l >> 4;
  int wr = (w >> 1) * 64, wc = (w & 1) * 64;

#define STAGE(buf, kk) do {                                                   \
    char* Ad = Asb + (buf) * 8192 + w * 1024;                                 \
    char* Bd = Bsb + (buf) * 8192 + w * 1024;                                 \
    _Pragma("unroll")                                                         \
    for (int j = 0; j < 2; ++j) {                                             \
      int idx = (j * 256 + tid) * 8; int r = idx >> 5, c = idx & 31;          \
      gload16(A + (size_t)(row0 + r) * lda + (kk) + c, Ad + j * 4096);        \
      gload16(W + (size_t)(col0 + r) * lda + (kk) + c, Bd + j * 4096);        \
    } } while (0)

  STAGE(0, k0);
  for (int t = 0; t < kiters; ++t) {
    int cur = t & 1;
    if (t + 1 < kiters) {
      STAGE(cur ^ 1, k0 + (t + 1) * 32);
      asm volatile("s_waitcnt vmcnt(4)" ::: "memory");
    } else {
      asm volatile("s_waitcnt vmcnt(0)" ::: "memory");
    }
    __builtin_amdgcn_s_barrier();
    asm volatile("" ::: "memory");
    const bf16_t* As = (const bf16_t*)(Asb + cur * 8192);
    const bf16_t* Bs = (const bf16_t*)(Bsb + cur * 8192);
    bf16x8 af[4], bfr[4];
#pragma unroll
    for (int m = 0; m < 4; ++m)
      af[m] = *(const bf16x8*)(As + (wr + 16 * m + l15) * 32 + lhi * 8);
#pragma unroll
    for (int n = 0; n < 4; ++n)
      bfr[n] = *(const bf16x8*)(Bs + (wc + 16 * n + l15) * 32 + lhi * 8);
#pragma unroll
    for (int m = 0; m < 4; ++m)
#pragma unroll
      for (int n = 0; n < 4; ++n)
        acc[m][n] = mfma16(af[m], bfr[n], acc[m][n]);
    asm volatile("s_waitcnt lgkmcnt(0)" ::: "memory");
    __builtin_amdgcn_s_barrier();
  }
#undef STAGE
}

// ---------------- fused QKV: grid (48, 32); V writes V^T via LDS transpose ----------------
__global__ __launch_bounds__(256, 4) void gemm_qkv(
    const bf16_t* __restrict__ A,
    const bf16_t* __restrict__ W0, const bf16_t* __restrict__ W1, const bf16_t* __restrict__ W2,
    const float* __restrict__ b0, const float* __restrict__ b1, const float* __restrict__ b2,
    bf16_t* __restrict__ qo, bf16_t* __restrict__ ko, bf16_t* __restrict__ vto) {
  __shared__ char smem[34816];   // staging 32KB | V-transpose 128x136 bf16
  char* Asb = smem;
  char* Bsb = smem + 16384;
  int bx = blockIdx.x;
  int wsel = bx >> 4, cb = bx & 15;
  const bf16_t* W    = wsel == 0 ? W0 : (wsel == 1 ? W1 : W2);
  const float*  bias = wsel == 0 ? b0 : (wsel == 1 ? b1 : b2);
  int row0 = blockIdx.y * 128, col0 = cb * 128;
  f32x4 acc[4][4] = {};
  gemm_core(A, W, 256, row0, col0, 0, 8, Asb, Bsb, acc);

  int tid = threadIdx.x, w = tid >> 6, l = tid & 63, l15 = l & 15, lhi = l >> 4;
  int wr = (w >> 1) * 64, wc = (w & 1) * 64;

  if (wsel < 2) {
    bf16_t* out = wsel == 0 ? qo : ko;
#pragma unroll
    for (int m = 0; m < 4; ++m)
#pragma unroll
      for (int n = 0; n < 4; ++n)
#pragma unroll
        for (int j = 0; j < 4; ++j) {
          int row = row0 + wr + 16 * m + lhi * 4 + j;
          int col = col0 + wc + 16 * n + l15;
          float v = acc[m][n][j] + bias[col];
          out[((size_t)((row >> 11) * 8 + (col >> 8)) * 2048 + (row & 2047)) * 256 + (col & 255)] = (bf16_t)v;
        }
  } else {
    // V: transpose in LDS, write V^T (B,H,Dh,S)
    __syncthreads();   // full drain before overwriting staging LDS
    bf16_t* T = (bf16_t*)smem;   // [128 d][136 stride] bf16
#pragma unroll
    for (int m = 0; m < 4; ++m)
#pragma unroll
      for (int n = 0; n < 4; ++n) {
        int d = wc + 16 * n + l15;
        int s = wr + 16 * m + lhi * 4;
        bf16x4 v4;
#pragma unroll
        for (int j = 0; j < 4; ++j) v4[j] = (bf16_t)(acc[m][n][j] + bias[col0 + d]);
        *(bf16x4*)(T + d * 136 + s) = v4;
      }
    __syncthreads();
    int bh = ((row0 >> 11) << 3) + (col0 >> 8);
    int d0 = col0 & 255, s0g = row0 & 2047;
#pragma unroll
    for (int p = 0; p < 8; ++p) {
      int idx = p * 256 + tid;
      int d = idx >> 4, c = (idx & 15) * 8;
      bf16x8 v8 = *(const bf16x8*)(T + d * 136 + c);
      *(bf16x8*)(vto + ((size_t)bh * 256 + d0 + d) * 2048 + s0g + c) = v8;
    }
  }
}

// ---------------- split-K partial GEMM: N=256, grid (2, 32, 4) ----------------
__global__ __launch_bounds__(256, 4) void gemm_part(
    const bf16_t* __restrict__ A, const bf16_t* __restrict__ W,
    int lda, int ksub, float* __restrict__ parts) {
  __shared__ char Asb[2 * 8192];
  __shared__ char Bsb[2 * 8192];
  int z = blockIdx.z;
  int row0 = blockIdx.y * 128, col0 = blockIdx.x * 128;
  f32x4 acc[4][4] = {};
  gemm_core(A, W, lda, row0, col0, z * ksub, ksub >> 5, Asb, Bsb, acc);

  int tid = threadIdx.x, w = tid >> 6, l = tid & 63, l15 = l & 15, lhi = l >> 4;
  int wr = (w >> 1) * 64, wc = (w & 1) * 64;
  float* p = parts + (size_t)z * 1048576;
#pragma unroll
  for (int m = 0; m < 4; ++m)
#pragma unroll
    for (int n = 0; n < 4; ++n)
#pragma unroll
      for (int j = 0; j < 4; ++j) {
        int row = row0 + wr + 16 * m + lhi * 4 + j;
        int col = col0 + wc + 16 * n + l15;
        p[(size_t)row * 256 + col] = acc[m][n][j];
      }
}

// ---------------- reduce 4 partials + bias + residual (final out) ----------------
__global__ __launch_bounds__(256) void reduce4(
    const float* __restrict__ parts, const float* __restrict__ bias,
    const float* __restrict__ res, float* __restrict__ out) {
  int i = blockIdx.x * 256 + threadIdx.x;
  f32x4 s = *(const f32x4*)(parts + (size_t)i * 4);
  s += *(const f32x4*)(parts + 1048576 + (size_t)i * 4);
  s += *(const f32x4*)(parts + 2097152 + (size_t)i * 4);
  s += *(const f32x4*)(parts + 3145728 + (size_t)i * 4);
  s += *(const f32x4*)(res + (size_t)i * 4);
  s += *(const f32x4*)(bias + (i & 63) * 4);
  *(f32x4*)(out + (size_t)i * 4) = s;
}

// ---------------- fused dense-reduce + residual + LN2 ----------------
__global__ __launch_bounds__(256) void reduce_ln(
    const float* __restrict__ parts, const float* __restrict__ bias,
    const float* __restrict__ res, const float* __restrict__ g,
    const float* __restrict__ bta, float* __restrict__ x1o, bf16_t* __restrict__ mo) {
  int row = blockIdx.x * 4 + (threadIdx.x >> 6);
  int l = threadIdx.x & 63;
  size_t base = (size_t)row * 256 + l * 4;
  f32x4 s = *(const f32x4*)(parts + base);
  s += *(const f32x4*)(parts + 1048576 + base);
  s += *(const f32x4*)(parts + 2097152 + base);
  s += *(const f32x4*)(parts + 3145728 + base);
  s += *(const f32x4*)(res + base);
  s += *(const f32x4*)(bias + l * 4);
  *(f32x4*)(x1o + base) = s;
  float sm = s[0] + s[1] + s[2] + s[3];
  float s2 = s[0]*s[0] + s[1]*s[1] + s[2]*s[2] + s[3]*s[3];
#pragma unroll
  for (int o = 1; o < 64; o <<= 1) { sm += __shfl_xor(sm, o, 64); s2 += __shfl_xor(s2, o, 64); }
  float m   = sm * (1.f/256.f);
  float var = s2 * (1.f/256.f) - m * m;
  float rs  = rsqrtf(var + 1e-9f);
  const float4 gv = *(const float4*)(g   + l * 4);
  const float4 bv = *(const float4*)(bta + l * 4);
  bf16x4 yb;
  yb[0] = (bf16_t)((s[0] - m) * rs * gv.x + bv.x);
  yb[1] = (bf16_t)((s[1] - m) * rs * gv.y + bv.y);
  yb[2] = (bf16_t)((s[2] - m) * rs * gv.z + bv.z);
  yb[3] = (bf16_t)((s[3] - m) * rs * gv.w + bv.w);
  *(bf16x4*)(mo + base) = yb;
}

// ---------------- FC1 with gelu ----------------
__global__ __launch_bounds__(256, 4) void gemm_fc1(
    const bf16_t* __restrict__ A, const bf16_t* __restrict__ W,
    const float* __restrict__ bias, bf16_t* __restrict__ out) {
  __shared__ char Asb[2 * 8192];
  __shared__ char Bsb[2 * 8192];
  int row0 = blockIdx.y * 128, col0 = blockIdx.x * 128;
  f32x4 acc[4][4] = {};
  gemm_core(A, W, 256, row0, col0, 0, 8, Asb, Bsb, acc);

  int tid = threadIdx.x, w = tid >> 6, l = tid & 63, l15 = l & 15, lhi = l >> 4;
  int wr = (w >> 1) * 64, wc = (w & 1) * 64;
#pragma unroll
  for (int m = 0; m < 4; ++m)
#pragma unroll
    for (int n = 0; n < 4; ++n)
#pragma unroll
      for (int j = 0; j < 4; ++j) {
        int row = row0 + wr + 16 * m + lhi * 4 + j;
        int col = col0 + wc + 16 * n + l15;
        float t = acc[m][n][j] + bias[col];
        float ge = 0.5f * t * (1.f + tanhf(0.7978845608f * t * (1.f + 0.044715f * t * t)));
        out[(size_t)row * 1024 + col] = (bf16_t)ge;
      }
}

// ---------------- fused attention v3: QBLK=32, TK=64, grid 1024 ----------------
// bh = bx&15, qt = 63 - (bx>>4) (descending work -> LPT backfill)
__global__ __launch_bounds__(256, 2) void attn_fused(
    const bf16_t* __restrict__ qg, const bf16_t* __restrict__ kg,
    const bf16_t* __restrict__ vt, float* __restrict__ pout,
    bf16_t* __restrict__ ctxo) {
  __shared__ __align__(16) char smem[74368];
  char*  Ksh   = smem;                       // 2 x 32KB K dbuf
  char*  Psh   = smem + 65536;               // 2 x 4KB P dbuf
  float* sl    = (float*)(smem + 73728);     // 4 x 32 f32
  float* invsh = (float*)(smem + 74240);     // 32 f32
  int bx = blockIdx.x;
  int bh = bx & 15, qt = 63 - (bx >> 4);
  int tid = threadIdx.x, w = tid >> 6, l = tid & 63;
  int l15 = l & 15, lhi = l >> 4;
  const bf16_t* Q = qg + (size_t)bh * 2048 * 256;
  const bf16_t* K = kg + (size_t)bh * 2048 * 256;
  const bf16_t* V = vt + (size_t)bh * 256 * 2048;
  int qbase = qt * 32;
  int nkt = (qt >> 1) + 1;   // TK=64 tiles covering k <= qbase+31

  // Q fragments: rows qbase + m*16 + l15
  bf16x8 qf[2][8];
#pragma unroll
  for (int m = 0; m < 2; ++m)
#pragma unroll
    for (int ks = 0; ks < 8; ++ks)
      qf[m][ks] = *(const bf16x8*)(Q + (size_t)(qbase + m * 16 + l15) * 256 + ks * 32 + lhi * 8);

  // K stage: dest buf (td&1), source tile ts. LDS linear dest, swizzled source:
  // LDS row r holds source cols permuted by ^((r&15)<<4) so reads at
  // row*512 + (col ^ ((row&15)<<4)) return linear K[row][col].
#define KSTAGE(td_, ts_) do {                                                  \
    char* dst0 = Ksh + ((td_) & 1) * 32768 + w * 1024;                         \
    _Pragma("unroll")                                                          \
    for (int j5 = 0; j5 < 8; ++j5) {                                           \
      int idx = j5 * 4096 + tid * 16; int r = idx >> 9; int inner = idx & 511; \
      int colb = inner ^ ((r & 15) << 4);                                      \
      gload16(K + (size_t)((ts_) * 64 + r) * 256 + (colb >> 1), dst0 + j5 * 4096); \
    } } while (0)

  int krow = w * 16 + l15;        // this lane's K row within tile (QK B-operand)
  int ksw  = (krow & 15) << 4;

  // ================= pass A: masked exp rowsums =================
  KSTAGE(0, 0);
  asm volatile("s_waitcnt vmcnt(0)" ::: "memory");
  __builtin_amdgcn_s_barrier();

  float sums[2][4] = {};
  for (int t = 0; t < nkt; ++t) {
    int tn = (t + 1 < nkt) ? t + 1 : nkt - 1;
    KSTAGE(t + 1, tn);
    const char* Kb = Ksh + (t & 1) * 32768;
    f32x4 acc[2] = {};
    __builtin_amdgcn_s_setprio(1);
#pragma unroll
    for (int ks = 0; ks < 8; ++ks) {
      bf16x8 kb = *(const bf16x8*)(Kb + krow * 512 + ((ks * 64 + lhi * 16) ^ ksw));
      acc[0] = mfma16(qf[0][ks], kb, acc[0]);
      acc[1] = mfma16(qf[1][ks], kb, acc[1]);
    }
    __builtin_amdgcn_s_setprio(0);
#pragma unroll
    for (int m = 0; m < 2; ++m)
#pragma unroll
      for (int j = 0; j < 4; ++j) {
        int qr = qbase + m * 16 + lhi * 4 + j;
        int kc = t * 64 + krow;
        sums[m][j] += (kc <= qr) ? __expf(acc[m][j] * 0.0625f) : 0.f;
      }
    asm volatile("s_waitcnt vmcnt(0)" ::: "memory");   // own KSTAGE(t+1) landed
    __builtin_amdgcn_s_barrier();
  }

#pragma unroll
  for (int m = 0; m < 2; ++m)
#pragma unroll
    for (int j = 0; j < 4; ++j)
#pragma unroll
      for (int o = 1; o < 16; o <<= 1)
        sums[m][j] += __shfl_xor(sums[m][j], o, 64);
  if (l15 == 0)
#pragma unroll
    for (int m = 0; m < 2; ++m)
#pragma unroll
      for (int j = 0; j < 4; ++j)
        sl[w * 32 + m * 16 + lhi * 4 + j] = sums[m][j];
  __syncthreads();
  if (tid < 32)
    invsh[tid] = 1.f / (sl[tid] + sl[32 + tid] + sl[64 + tid] + sl[96 + tid]);
  __syncthreads();
  float inv4[2][4];
#pragma unroll
  for (int m = 0; m < 2; ++m)
#pragma unroll
    for (int j = 0; j < 4; ++j)
      inv4[m][j] = invsh[m * 16 + lhi * 4 + j];

  // ================= pass B: QK -> P(dump+LDS) -> PV; 1 barrier/tile =========
  KSTAGE(0, 0);
  asm volatile("s_waitcnt vmcnt(0)" ::: "memory");
  __builtin_amdgcn_s_barrier();

  f32x4 ctx[2][4] = {};
  for (int t = 0; t < nkt; ++t) {
    int tn = (t + 1 < nkt) ? t + 1 : nkt - 1;
    KSTAGE(t + 1, tn);                                  // 8 vm (oldest this iter)
    // V fragments direct from global (L2); consumed after barrier
    bf16x8 vb[4][2];
#pragma unroll
    for (int n4 = 0; n4 < 4; ++n4)
#pragma unroll
      for (int ks2 = 0; ks2 < 2; ++ks2)
        vb[n4][ks2] = *(const bf16x8*)(V + (size_t)(w * 64 + n4 * 16 + l15) * 2048 + t * 64 + ks2 * 32 + lhi * 8);

    // QK: all 32 rows x this wave's 16-col strip
    const char* Kb = Ksh + (t & 1) * 32768;
    f32x4 acc[2] = {};
    __builtin_amdgcn_s_setprio(1);
#pragma unroll
    for (int ks = 0; ks < 8; ++ks) {
      bf16x8 kb = *(const bf16x8*)(Kb + krow * 512 + ((ks * 64 + lhi * 16) ^ ksw));
      acc[0] = mfma16(qf[0][ks], kb, acc[0]);
      acc[1] = mfma16(qf[1][ks], kb, acc[1]);
    }
    __builtin_amdgcn_s_setprio(0);

    // exp/normalize/mask; dump f32 from regs; write bf16 to Psh[t&1]
    char* Pb = Psh + (t & 1) * 4096;
#pragma unroll
    for (int m = 0; m < 2; ++m)
#pragma unroll
      for (int j = 0; j < 4; ++j) {
        int rr = m * 16 + lhi * 4 + j;
        int qr = qbase + rr;
        int kc = t * 64 + krow;
        float e = (kc <= qr) ? __expf(acc[m][j] * 0.0625f) * inv4[m][j] : 0.f;
        pout[((size_t)bh * 2048 + qr) * 2048 + kc] = e;
        *(bf16_t*)(Pb + rr * 128 + ((krow * 2) ^ (lhi << 5))) = (bf16_t)e;
      }
    asm volatile("s_waitcnt lgkmcnt(0)" ::: "memory");  // P ds_writes visible
    asm volatile("s_waitcnt vmcnt(16)" ::: "memory");   // KSTAGE(t+1) done (vb+dumps may fly)
    __builtin_amdgcn_s_barrier();

    // PV: rows 32 x d-cols [w*64,+64)
    __builtin_amdgcn_s_setprio(1);
#pragma unroll
    for (int ks2 = 0; ks2 < 2; ++ks2) {
      bf16x8 pa[2];
#pragma unroll
      for (int m = 0; m < 2; ++m) {
        int pr = m * 16 + l15;
        pa[m] = *(const bf16x8*)(Pb + pr * 128 + ((ks2 * 64 + lhi * 16) ^ (((pr >> 2) & 3) << 5)));
      }
#pragma unroll
      for (int m = 0; m < 2; ++m)
#pragma unroll
        for (int n4 = 0; n4 < 4; ++n4)
          ctx[m][n4] = mfma16(pa[m], vb[n4][ks2], ctx[m][n4]);
    }
    __builtin_amdgcn_s_setprio(0);
  }
#undef KSTAGE

  // ctx write: (b, s, h*256 + d) bf16
  int b = bh >> 3, h = bh & 7;
#pragma unroll
  for (int m = 0; m < 2; ++m)
#pragma unroll
    for (int n4 = 0; n4 < 4; ++n4)
#pragma unroll
      for (int j = 0; j < 4; ++j) {
        int qr = qbase + m * 16 + lhi * 4 + j;
        ctxo[((size_t)b * 2048 + qr) * 2048 + h * 256 + w * 64 + n4 * 16 + l15] = (bf16_t)ctx[m][n4][j];
      }

  // zero-fill masked region beyond staged tiles
  int zs = nkt * 64;
  for (int r = 0; r < 32; ++r) {
    size_t base2 = ((size_t)bh * 2048 + qbase + r) * 2048;
    for (int c = zs + tid * 4; c < 2048; c += 1024)
      *(float4*)(pout + base2 + c) = make_float4(0.f, 0.f, 0.f, 0.f);
  }
}

// ---------------- host launch ----------------
extern "C" void kernel_launch(void* const* d_in, const int* in_sizes, int n_in,
                              void* d_out, int out_size, void* d_ws, size_t ws_size,
                              hipStream_t stream) {
  const float* x     = (const float*)d_in[0];
  const float* ln1g  = (const float*)d_in[2];
  const float* ln1b  = (const float*)d_in[3];
  const float* wq_w  = (const float*)d_in[4];
  const float* wq_b  = (const float*)d_in[5];
  const float* wk_w  = (const float*)d_in[6];
  const float* wk_b  = (const float*)d_in[7];
  const float* wv_w  = (const float*)d_in[8];
  const float* wv_b  = (const float*)d_in[9];
  const float* dw    = (const float*)d_in[10];
  const float* db    = (const float*)d_in[11];
  const float* ln2g  = (const float*)d_in[12];
  const float* ln2b  = (const float*)d_in[13];
  const float* f1w   = (const float*)d_in[14];
  const float* f1b   = (const float*)d_in[15];
  const float* f2w   = (const float*)d_in[16];
  const float* f2b   = (const float*)d_in[17];

  char* ws = (char*)d_ws;
  const size_t MB = 1u << 20;
  float*  xn_f = (float*) (ws + 0 * MB);
  bf16_t* xn_b = (bf16_t*)(ws + 4 * MB);
  bf16_t* q_b  = (bf16_t*)(ws + 6 * MB);
  bf16_t* k_b  = (bf16_t*)(ws + 22 * MB);
  bf16_t* ctx_b= (bf16_t*)(ws + 38 * MB);
  bf16_t* vt_b = (bf16_t*)(ws + 54 * MB);
  float*  x1_f = (float*) (ws + 70 * MB);
  bf16_t* m_b  = (bf16_t*)(ws + 74 * MB);
  bf16_t* h_b  = (bf16_t*)(ws + 76 * MB);
  bf16_t* wq_bf = (bf16_t*)(ws + 84 * MB);
  bf16_t* wk_bf = wq_bf + 524288;
  bf16_t* wv_bf = wk_bf + 524288;
  bf16_t* dw_bf = wv_bf + 524288;
  bf16_t* f1_bf = dw_bf + 524288;
  bf16_t* f2_bf = f1_bf + 262144;
  float* parts_d = (float*)q_b;
  float* parts_f = (float*)k_b;

  float* out0 = (float*)d_out;
  float* pout = out0 + 1048576;

  k1_lncvt<<<3584, 256, 0, stream>>>(x, ln1g, ln1b, xn_f, xn_b,
                                     wq_w, wk_w, wv_w, dw, f1w, f2w,
                                     wq_bf, wk_bf, wv_bf, dw_bf, f1_bf, f2_bf);

  gemm_qkv<<<dim3(48, 32), 256, 0, stream>>>(xn_b, wq_bf, wk_bf, wv_bf,
                                             wq_b, wk_b, wv_b, q_b, k_b, vt_b);

  attn_fused<<<1024, 256, 0, stream>>>(q_b, k_b, vt_b, pout, ctx_b);

  gemm_part<<<dim3(2, 32, 4), 256, 0, stream>>>(ctx_b, dw_bf, 2048, 512, parts_d);
  reduce_ln<<<1024, 256, 0, stream>>>(parts_d, db, xn_f, ln2g, ln2b, x1_f, m_b);

  gemm_fc1<<<dim3(8, 32), 256, 0, stream>>>(m_b, f1_bf, f1b, h_b);

  gemm_part<<<dim3(2, 32, 4), 256, 0, stream>>>(h_b, f2_bf, 1024, 256, parts_f);
  reduce4<<<1024, 256, 0, stream>>>(parts_f, f2b, x1_f, out0);
}